// Round 3
// baseline (138.534 us; speedup 1.0000x reference)
//
#include <hip/hip_runtime.h>

// Problem constants (from reference): A=5, B=2, K=5, C=13, H=W=256
constexpr int A_ = 5, B_ = 2, K_ = 5, C_ = 13, H_ = 256, W_ = 256;
constexpr int HW_ = H_ * W_;
constexpr int TILE = 16;
constexpr int REG = TILE + 1;            // 17 (tile + 1 halo for pass-2 taps)
constexpr int NPOS = REG * REG;          // 289
constexpr int NT = 256;
constexpr int PPT = 2;                   // ceil(289/256)
constexpr int BCAP = 4096;               // bbox LDS capacity in floats (16 KB)

__global__ __launch_bounds__(NT)
void fafmimo_warp_kernel(const float* __restrict__ bevs,
                         const float* __restrict__ tm,
                         const int*   __restrict__ nat,
                         const int*   __restrict__ center_p,
                         float* __restrict__ out)
{
    const int tileIdx = blockIdx.x;      // 0..255 (16x16 tiles of 16x16 px)
    const int abk     = blockIdx.y;      // 0..49 == (a*B+b)*K + k
    const int a   = abk / (B_ * K_);
    const int rem = abk % (B_ * K_);
    const int b   = rem / K_;
    const int k   = rem % K_;

    const int center  = center_p[0];
    const int n_agent = nat[b * A_ + center];
    const bool masked = (a < n_agent) && ((a != center) || (k == K_ - 1));

    const int th0 = (tileIdx >> 4) * TILE;
    const int tw0 = (tileIdx & 15) * TILE;

    const int tid  = threadIdx.x;
    const int pr_o = tid >> 4;           // output row within tile
    const int pc_o = tid & 15;           // output col within tile
    const int pix  = (th0 + pr_o) * W_ + tw0 + pc_o;

    const size_t imgBase = (size_t)abk * C_ * HW_;
    const float* img = bevs + imgBase;
    float*       o   = out  + imgBase;

    if (!masked) {
        // vectorized copy: tid -> (channel lane c4, row r, float4 quad q)
        const int c4 = tid >> 6;         // 0..3
        const int r  = (tid >> 2) & 15;  // 0..15
        const int q  = tid & 3;          // 0..3
        const int off0 = (th0 + r) * W_ + tw0 + (q << 2);
        #pragma unroll
        for (int c = c4; c < C_; c += 4) {
            const float4 v = *reinterpret_cast<const float4*>(img + c * HW_ + off0);
            *reinterpret_cast<float4*>(o + c * HW_ + off0) = v;
        }
        return;
    }

    // --- per-image transform params (trans_mats shape (A,K,B,4,4)) ---
    const int tb = ((a * K_ + k) * B_ + b) * 16;
    const float t00 = tm[tb + 0], t01 = tm[tb + 1], t03 = tm[tb + 3];
    const float t10 = tm[tb + 4], t11 = tm[tb + 5], t13 = tm[tb + 7];

    // Pass-2 translation in pixel units
    const float dx = 4.0f * t03;
    const float dy = -4.0f * t13;
    const float fxf = floorf(dx), fyf = floorf(dy);
    const int   fx = (int)fxf,    fy = (int)fyf;
    const float wx2 = dx - fxf,   wy2 = dy - fyf;
    const float w00 = (1.0f - wx2) * (1.0f - wy2);
    const float w01 = wx2 * (1.0f - wy2);
    const float w10 = (1.0f - wx2) * wy2;
    const float w11 = wx2 * wy2;

    // S1 region origin (integer pixels)
    const int gy0 = th0 + fy;
    const int gx0 = tw0 + fx;

    // source coords: ix = t00*(gx+0.5) + t01*(gy+0.5) - 128*(t00+t01) + 127.5
    const float cxk = 127.5f - 127.5f * (t00 + t01);
    const float cyk = 127.5f - 127.5f * (t10 + t11);

    // --- bounding box of source taps over the whole REGxREG region ---
    const float ixA = t00 * (float)gx0 + t01 * (float)gy0 + cxk;
    const float iyA = t10 * (float)gx0 + t11 * (float)gy0 + cyk;
    const float exx = t00 * (float)(REG - 1), exy = t01 * (float)(REG - 1);
    const float eyx = t10 * (float)(REG - 1), eyy = t11 * (float)(REG - 1);
    const float ixmin = ixA + fminf(exx, 0.f) + fminf(exy, 0.f);
    const float ixmax = ixA + fmaxf(exx, 0.f) + fmaxf(exy, 0.f);
    const float iymin = iyA + fminf(eyx, 0.f) + fminf(eyy, 0.f);
    const float iymax = iyA + fmaxf(eyx, 0.f) + fmaxf(eyy, 0.f);
    const int bx0 = min(max((int)floorf(ixmin), 0), W_ - 1);
    const int bx1 = min(max((int)floorf(ixmax) + 1, 0), W_ - 1);
    const int by0 = min(max((int)floorf(iymin), 0), H_ - 1);
    const int by1 = min(max((int)floorf(iymax) + 1, 0), H_ - 1);
    const int Lw  = bx1 - bx0 + 1;
    const int nry = by1 - by0 + 1;
    const bool fit = (Lw * nry <= BCAP);

    // --- per-position taps for the 17x17 S1 region (channel-independent) ---
    int   f0[PPT], f1[PPT], f2[PPT], f3[PPT];
    float q0[PPT], q1[PPT], q2[PPT], q3[PPT];
    bool  hasAny = false;
    #pragma unroll
    for (int it = 0; it < PPT; ++it) {
        const int p = tid + it * NT;
        const int pr = p / REG;
        const int pc = p - pr * REG;
        const int gyp = gy0 + pr;
        const int gxp = gx0 + pc;
        const bool inreg = (p < NPOS) &&
                           (gyp >= 0) && (gyp < H_) && (gxp >= 0) && (gxp < W_);
        const float ix = t00 * (float)gxp + t01 * (float)gyp + cxk;
        const float iy = t10 * (float)gxp + t11 * (float)gyp + cyk;
        const float x0f = floorf(ix), y0f = floorf(iy);
        const float wx = ix - x0f,    wy = iy - y0f;
        const int x0 = (int)x0f, y0 = (int)y0f;
        const int x1 = x0 + 1,   y1 = y0 + 1;
        const bool vx0 = (x0 >= 0) && (x0 < W_);
        const bool vx1 = (x1 >= 0) && (x1 < W_);
        const bool vy0 = (y0 >= 0) && (y0 < H_);
        const bool vy1 = (y1 >= 0) && (y1 < H_);
        const int cx0 = min(max(x0, 0), W_ - 1);
        const int cx1 = min(max(x1, 0), W_ - 1);
        const int cy0 = min(max(y0, 0), H_ - 1);
        const int cy1 = min(max(y1, 0), H_ - 1);
        if (fit) {
            f0[it] = (cy0 - by0) * Lw + (cx0 - bx0);
            f1[it] = (cy0 - by0) * Lw + (cx1 - bx0);
            f2[it] = (cy1 - by0) * Lw + (cx0 - bx0);
            f3[it] = (cy1 - by0) * Lw + (cx1 - bx0);
        } else {
            f0[it] = cy0 * W_ + cx0;
            f1[it] = cy0 * W_ + cx1;
            f2[it] = cy1 * W_ + cx0;
            f3[it] = cy1 * W_ + cx1;
        }
        const float m = inreg ? 1.0f : 0.0f;
        q0[it] = (1.0f - wx) * (1.0f - wy) * ((vx0 && vy0) ? m : 0.0f);
        q1[it] = wx * (1.0f - wy)          * ((vx1 && vy0) ? m : 0.0f);
        q2[it] = (1.0f - wx) * wy          * ((vx0 && vy1) ? m : 0.0f);
        q3[it] = wx * wy                   * ((vx1 && vy1) ? m : 0.0f);
        hasAny |= (q0[it] != 0.f) || (q1[it] != 0.f) || (q2[it] != 0.f) || (q3[it] != 0.f);
    }

    __shared__ float sBox[BCAP];
    __shared__ float sS1[NPOS];
    __shared__ int   anyflag;

    if (tid == 0) anyflag = 0;
    __syncthreads();
    if (hasAny) anyflag = 1;             // benign race: all writers store 1
    __syncthreads();

    if (!anyflag) {
        #pragma unroll
        for (int c = 0; c < C_; ++c) o[c * HW_ + pix] = 0.0f;
        return;
    }

    if (fit) {
        for (int c = 0; c < C_; ++c) {
            const float* __restrict__ imgc = img + c * HW_;
            // stage bbox rows, coalesced (half-wave per row stripe)
            for (int r = tid >> 5; r < nry; r += 8) {
                const float* __restrict__ src = imgc + (by0 + r) * W_ + bx0;
                float* __restrict__ dst = sBox + r * Lw;
                for (int cc = tid & 31; cc < Lw; cc += 32)
                    dst[cc] = src[cc];
            }
            __syncthreads();
            // pass 1 from LDS bbox
            #pragma unroll
            for (int it = 0; it < PPT; ++it) {
                const int p = tid + it * NT;
                if (p < NPOS) {
                    sS1[p] = q0[it] * sBox[f0[it]] + q1[it] * sBox[f1[it]]
                           + q2[it] * sBox[f2[it]] + q3[it] * sBox[f3[it]];
                }
            }
            __syncthreads();
            // pass 2: constant-weight 2x2 blend
            const float* Lr = sS1 + pr_o * REG + pc_o;
            o[c * HW_ + pix] = w00 * Lr[0] + w01 * Lr[1]
                             + w10 * Lr[REG] + w11 * Lr[REG + 1];
            // next stage writes sBox only after the next barrier; safe
        }
    } else {
        // rare fallback: direct global gather
        for (int c = 0; c < C_; ++c) {
            const float* __restrict__ imgc = img + c * HW_;
            #pragma unroll
            for (int it = 0; it < PPT; ++it) {
                const int p = tid + it * NT;
                if (p < NPOS) {
                    sS1[p] = q0[it] * imgc[f0[it]] + q1[it] * imgc[f1[it]]
                           + q2[it] * imgc[f2[it]] + q3[it] * imgc[f3[it]];
                }
            }
            __syncthreads();
            const float* Lr = sS1 + pr_o * REG + pc_o;
            o[c * HW_ + pix] = w00 * Lr[0] + w01 * Lr[1]
                             + w10 * Lr[REG] + w11 * Lr[REG + 1];
            __syncthreads();
        }
    }
}

extern "C" void kernel_launch(void* const* d_in, const int* in_sizes, int n_in,
                              void* d_out, int out_size, void* d_ws, size_t ws_size,
                              hipStream_t stream) {
    const float* bevs   = (const float*)d_in[0];
    const float* tm     = (const float*)d_in[1];
    const int*   nat    = (const int*)d_in[2];
    const int*   center = (const int*)d_in[4];
    float* out = (float*)d_out;

    dim3 grid((H_ / TILE) * (W_ / TILE), A_ * B_ * K_);
    dim3 block(NT);
    fafmimo_warp_kernel<<<grid, block, 0, stream>>>(bevs, tm, nat, center, out);
}

// Round 4
// 95.371 us; speedup vs baseline: 1.4526x; 1.4526x over previous
//
#include <hip/hip_runtime.h>

// Problem constants (from reference): A=5, B=2, K=5, C=13, H=W=256
constexpr int A_ = 5, B_ = 2, K_ = 5, C_ = 13, H_ = 256, W_ = 256;
constexpr int HW_ = H_ * W_;
constexpr int TILE = 32;
constexpr int REG = TILE + 1;            // 33 (tile + 1 halo for pass-2 taps)
constexpr int NPOS = REG * REG;          // 1089
constexpr int NT = 256;
constexpr int PPT = (NPOS + NT - 1) / NT; // 5 positions per thread

__global__ __launch_bounds__(NT)
void fafmimo_warp_kernel(const float* __restrict__ bevs,
                         const float* __restrict__ tm,
                         const int*   __restrict__ nat,
                         const int*   __restrict__ center_p,
                         float* __restrict__ out)
{
    const int tileIdx = blockIdx.x;      // 0..63 (8x8 tiles of 32x32)
    const int abk     = blockIdx.y;      // 0..49 == (a*B+b)*K + k
    const int ch      = blockIdx.z;      // 0..12
    const int a   = abk / (B_ * K_);
    const int rem = abk % (B_ * K_);
    const int b   = rem / K_;
    const int k   = rem % K_;

    const int center  = center_p[0];
    const int n_agent = nat[b * A_ + center];
    const bool masked = (a < n_agent) && ((a != center) || (k == K_ - 1));

    const int th0 = (tileIdx >> 3) * TILE;
    const int tw0 = (tileIdx & 7) * TILE;

    const int tid = threadIdx.x;
    const int rr  = tid >> 3;            // output row within tile, 0..31
    const int cg  = (tid & 7) << 2;      // output col group (float4), 0..28

    const float* __restrict__ img = bevs + (size_t)abk * C_ * HW_ + (size_t)ch * HW_;
    float*       __restrict__ o   = out  + (size_t)abk * C_ * HW_ + (size_t)ch * HW_;
    const int off = (th0 + rr) * W_ + tw0 + cg;

    if (!masked) {
        // straight copy of this channel tile (float4, coalesced)
        const float4 v = *reinterpret_cast<const float4*>(img + off);
        *reinterpret_cast<float4*>(o + off) = v;
        return;
    }

    // --- per-image transform params (trans_mats shape (A,K,B,4,4)) ---
    const int tb = ((a * K_ + k) * B_ + b) * 16;
    const float t00 = tm[tb + 0], t01 = tm[tb + 1], t03 = tm[tb + 3];
    const float t10 = tm[tb + 4], t11 = tm[tb + 5], t13 = tm[tb + 7];

    // Pass-2 (translation) in pixel units
    const float dx = 4.0f * t03;
    const float dy = -4.0f * t13;
    const float fxf = floorf(dx), fyf = floorf(dy);
    const int   fx = (int)fxf,    fy = (int)fyf;
    const float wx2 = dx - fxf,   wy2 = dy - fyf;
    const float w00 = (1.0f - wx2) * (1.0f - wy2);
    const float w01 = wx2 * (1.0f - wy2);
    const float w10 = (1.0f - wx2) * wy2;
    const float w11 = wx2 * wy2;

    __shared__ float lds[NPOS];
    __shared__ int   anyflag;
    if (tid == 0) anyflag = 0;

    // --- pass-1 taps for the 33x33 S1 region ---
    int   o0[PPT], o1[PPT], o2[PPT], o3[PPT];
    float q0[PPT], q1[PPT], q2[PPT], q3[PPT];
    bool  hasAny = false;
    #pragma unroll
    for (int it = 0; it < PPT; ++it) {
        const int p = tid + it * NT;
        const int pr = p / REG;
        const int pc = p - pr * REG;
        const int gyp = th0 + fy + pr;
        const int gxp = tw0 + fx + pc;
        const bool inreg = (p < NPOS) &&
                           (gyp >= 0) && (gyp < H_) && (gxp >= 0) && (gxp < W_);
        const float Xc = ((float)gxp + 0.5f) * (1.0f / 128.0f) - 1.0f;
        const float Yc = ((float)gyp + 0.5f) * (1.0f / 128.0f) - 1.0f;
        const float gx = t00 * Xc + t01 * Yc;
        const float gy = t10 * Xc + t11 * Yc;
        const float ix = gx * 128.0f + 127.5f;
        const float iy = gy * 128.0f + 127.5f;
        const float x0f = floorf(ix), y0f = floorf(iy);
        const float wx = ix - x0f,    wy = iy - y0f;
        const int x0 = (int)x0f, y0 = (int)y0f;
        const int x1 = x0 + 1,   y1 = y0 + 1;
        const bool vx0 = (x0 >= 0) && (x0 < W_);
        const bool vx1 = (x1 >= 0) && (x1 < W_);
        const bool vy0 = (y0 >= 0) && (y0 < H_);
        const bool vy1 = (y1 >= 0) && (y1 < H_);
        const int cx0 = min(max(x0, 0), W_ - 1);
        const int cx1 = min(max(x1, 0), W_ - 1);
        const int cy0 = min(max(y0, 0), H_ - 1);
        const int cy1 = min(max(y1, 0), H_ - 1);
        o0[it] = cy0 * W_ + cx0;
        o1[it] = cy0 * W_ + cx1;
        o2[it] = cy1 * W_ + cx0;
        o3[it] = cy1 * W_ + cx1;
        const float m = inreg ? 1.0f : 0.0f;
        q0[it] = (1.0f - wx) * (1.0f - wy) * ((vx0 && vy0) ? m : 0.0f);
        q1[it] = wx * (1.0f - wy)          * ((vx1 && vy0) ? m : 0.0f);
        q2[it] = (1.0f - wx) * wy          * ((vx0 && vy1) ? m : 0.0f);
        q3[it] = wx * wy                   * ((vx1 && vy1) ? m : 0.0f);
        hasAny |= (q0[it] != 0.f) || (q1[it] != 0.f) ||
                  (q2[it] != 0.f) || (q3[it] != 0.f);
    }

    __syncthreads();
    if (hasAny) anyflag = 1;             // benign race: all writers store 1
    __syncthreads();

    if (!anyflag) {
        // whole S1 region has zero weight -> this channel tile is zeros
        *reinterpret_cast<float4*>(o + off) = make_float4(0.f, 0.f, 0.f, 0.f);
        return;
    }

    // pass 1: gather into LDS (20 independent loads in flight per thread)
    #pragma unroll
    for (int it = 0; it < PPT; ++it) {
        const int p = tid + it * NT;
        const float s = q0[it] * img[o0[it]] + q1[it] * img[o1[it]]
                      + q2[it] * img[o2[it]] + q3[it] * img[o3[it]];
        if (p < NPOS) lds[p] = s;
    }
    __syncthreads();

    // pass 2: constant-weight 2x2 blend from LDS, 4 outputs per thread
    const float* Lr0 = lds + rr * REG + cg;
    const float* Lr1 = Lr0 + REG;
    const float l0 = Lr0[0], l1 = Lr0[1], l2 = Lr0[2], l3 = Lr0[3], l4 = Lr0[4];
    const float m0 = Lr1[0], m1 = Lr1[1], m2 = Lr1[2], m3 = Lr1[3], m4 = Lr1[4];
    float4 v;
    v.x = w00 * l0 + w01 * l1 + w10 * m0 + w11 * m1;
    v.y = w00 * l1 + w01 * l2 + w10 * m1 + w11 * m2;
    v.z = w00 * l2 + w01 * l3 + w10 * m2 + w11 * m3;
    v.w = w00 * l3 + w01 * l4 + w10 * m3 + w11 * m4;
    *reinterpret_cast<float4*>(o + off) = v;
}

extern "C" void kernel_launch(void* const* d_in, const int* in_sizes, int n_in,
                              void* d_out, int out_size, void* d_ws, size_t ws_size,
                              hipStream_t stream) {
    const float* bevs   = (const float*)d_in[0];
    const float* tm     = (const float*)d_in[1];
    const int*   nat    = (const int*)d_in[2];
    const int*   center = (const int*)d_in[4];
    float* out = (float*)d_out;

    dim3 grid((H_ / TILE) * (W_ / TILE), A_ * B_ * K_, C_);
    dim3 block(NT);
    fafmimo_warp_kernel<<<grid, block, 0, stream>>>(bevs, tm, nat, center, out);
}